// Round 8
// baseline (1143.293 us; speedup 1.0000x reference)
//
#include <hip/hip_runtime.h>
#include <cstdint>
#include <cstddef>

// ---------------------------------------------------------------------------
// EncoderLayer: B=8 S=1024 D=2048 H=16 Dh=128 FF=8192, fp32 in/out, bf16 compute
// ---------------------------------------------------------------------------

typedef unsigned short u16;
typedef unsigned int   u32;
typedef unsigned long long u64;
typedef __attribute__((ext_vector_type(8))) short short8;   // 8 x bf16 (4 VGPR)
typedef __attribute__((ext_vector_type(4))) float f32x4;

constexpr int Bc  = 8;
constexpr int Sc  = 1024;
constexpr int Dc  = 2048;
constexpr int Hc  = 16;
constexpr int Dhc = 128;
constexpr int FFc = 8192;
constexpr int Mc  = Bc * Sc;   // 8192 rows

// ---- bf16 helpers (manual, RNE) -------------------------------------------
__device__ __forceinline__ u16 f2b(float f) {
  u32 u = __builtin_bit_cast(u32, f);
  u += 0x7fffu + ((u >> 16) & 1u);
  return (u16)(u >> 16);
}
__device__ __forceinline__ u32 pack2(float a, float b) {
  return (u32)f2b(a) | ((u32)f2b(b) << 16);
}
__device__ __forceinline__ void unpack8(uint4 u, float* f) {
  u32 w[4] = {u.x, u.y, u.z, u.w};
#pragma unroll
  for (int i = 0; i < 4; ++i) {
    f[2 * i + 0] = __builtin_bit_cast(float, w[i] << 16);
    f[2 * i + 1] = __builtin_bit_cast(float, w[i] & 0xffff0000u);
  }
}

#define GLOAD_LDS16(gp, lp)                                                    \
  __builtin_amdgcn_global_load_lds(                                            \
      (const __attribute__((address_space(1))) void*)(gp),                     \
      (__attribute__((address_space(3))) void*)(lp), 16, 0, 0)

// ---- f32 -> bf16 conversion -----------------------------------------------
__global__ __launch_bounds__(256) void cvt_f32_bf16(const float* __restrict__ in,
                                                    u16* __restrict__ out, int n) {
  int i = (blockIdx.x * 256 + threadIdx.x) << 2;
  if (i >= n) return;
  float4 v = *(const float4*)(in + i);
  ushort4 o;
  o.x = f2b(v.x); o.y = f2b(v.y); o.z = f2b(v.z); o.w = f2b(v.w);
  *(ushort4*)(out + i) = o;
}

// ---- mask -> bitmask: mb[s][w] bit i = (mask[s][w*64+i] != 0) --------------
__global__ __launch_bounds__(256) void mask_bits(const int* __restrict__ mask,
                                                 u64* __restrict__ mb) {
  int t = blockIdx.x * 256 + threadIdx.x;   // 16384 = 1024 * 16
  int r = t >> 4, wd = t & 15;
  const int* p = mask + (size_t)r * Sc + wd * 64;
  u64 bits = 0;
#pragma unroll 16
  for (int i = 0; i < 64; i += 4) {
    int4 q = *(const int4*)(p + i);
    bits |= (u64)(q.x != 0) << (i + 0);
    bits |= (u64)(q.y != 0) << (i + 1);
    bits |= (u64)(q.z != 0) << (i + 2);
    bits |= (u64)(q.w != 0) << (i + 3);
  }
  mb[t] = bits;
}

// ---- 256x256 bf16 GEMM, phase-pair pipeline --------------------------------
// 8 waves (2Mx4N), BK=32, 4 LDS tile buffers (128 KB), st_16x32 swizzle.
// Iteration t (tile t from ring[t&3]) = TWO phases of 16 MFMA, each with the
// m201 barrier pattern: {ds_reads(own) + 1 gload pair -> s_barrier ->
// lgkmcnt(0) -> sched_barrier(0) -> setprio(1) 16 MFMA setprio(0) -> s_barrier}
// Phase 0: bF+aF[0..3], stage A(t+3), MFMA acc[0..3].
// Phase 1: aF[4..7],     stage B(t+3), MFMA acc[4..7], counted gate.
// The double-barrier phase split staggers wave roles so one wave's LDS drain
// overlaps another's MFMA (T3/T5 regime); loads stay in flight across
// barriers via counted vmcnt(4) (T4), vmcnt(0) only at the tail.
// Ledger (unchanged from rounds 5-7, proven deterministic): tile u staged at
// iter u-3; end-of-iter-(u-2) gate vmcnt(4) leaves only tile (u+1)'s 4 loads
// outstanding -> tile u landed, with >= 4 barriers before its reads. WAR:
// ring[x] reads (iter u, lgkm-drained before final barrier) precede next
// write (iter u+1 issue region, after that barrier).
// MODE 0: bf16 out. MODE 1: ReLU + bf16 out. MODE 2: vt[b][h][d][s] write.
template <int MODE>
__global__ __launch_bounds__(512, 2) void gemm256tb(const u16* __restrict__ A,
                                                    const u16* __restrict__ Bt,
                                                    const float* __restrict__ bias,
                                                    u16* __restrict__ C,
                                                    int M, int N, int K) {
  __shared__ u16 Abuf[4][256 * 32];   // 64 KB
  __shared__ u16 Bbuf[4][256 * 32];   // 64 KB

  const int nbn = N >> 8;
  const int nwg = (M >> 8) * nbn;
  int bid = blockIdx.x;
  int sw = (bid & 7) * (nwg >> 3) + (bid >> 3);   // nwg multiple of 8 always
  const int m0 = (sw / nbn) << 8;
  const int n0 = (sw % nbn) << 8;

  const int tid  = threadIdx.x;
  const int lane = tid & 63;
  const int w    = tid >> 6;        // wave 0..7
  const int wm   = w >> 2;          // 0..1  (M half)
  const int wn   = w & 3;           // 0..3  (N quarter)

  const int rowA = lane & 15;
  const int g4   = lane >> 4;

  // Stage-source pre-swizzle (write side of st_16x32, inverse applied to the
  // per-lane global source so the LDS dest stays linear).
  const int p16  = lane << 4;
  const int wsw  = p16 ^ (((p16 >> 9) & 1) << 5);
  const int s_rr = wsw >> 6;            // row 0..15 within subtile
  const int s_cc = (wsw & 63) >> 1;     // col elem 0/8/16/24

  // ds_read swizzled byte offset within a 1024B subtile (read side)
  const int sb = (rowA * 64 + g4 * 16) ^ (((rowA >> 3) & 1) << 5);

  const int NT = K >> 5;   // K-tiles (64 or 256 here)

  const u16* Asrc = A  + (size_t)(m0 + w * 32 + s_rr) * K + s_cc;
  const u16* Bsrc = Bt + (size_t)(n0 + w * 32 + s_rr) * K + s_cc;

  // wave w stages subtiles 2w, 2w+1 (rows w*32 .. w*32+31) of a 256x32 tile
  auto stageA = [&](int tt) {
    int buf = tt & 3;
#pragma unroll
    for (int i = 0; i < 2; ++i)
      GLOAD_LDS16(Asrc + (size_t)i * 16 * K + tt * 32, &Abuf[buf][(2 * w + i) * 512]);
  };
  auto stageB = [&](int tt) {
    int buf = tt & 3;
#pragma unroll
    for (int i = 0; i < 2; ++i)
      GLOAD_LDS16(Bsrc + (size_t)i * 16 * K + tt * 32, &Bbuf[buf][(2 * w + i) * 512]);
  };

  f32x4 acc[8][4];
#pragma unroll
  for (int m = 0; m < 8; ++m)
#pragma unroll
    for (int n = 0; n < 4; ++n) acc[m][n] = (f32x4){0.f, 0.f, 0.f, 0.f};

  // Prologue: stage tiles 0,1,2 (12 gloads); vmcnt(4) -> tiles 0,1 landed.
  stageA(0); stageB(0);
  stageA(1); stageB(1);
  stageA(2); stageB(2);
  asm volatile("s_waitcnt vmcnt(4)" ::: "memory");
  __builtin_amdgcn_s_barrier();

  for (int t = 0; t < NT; ++t) {
    const int buf = t & 3;
    const bool st = (t + 3) < NT;

    // ---- phase 0: reads bF[all] + aF[0..3]; stage A(t+3); 16 MFMA ----------
    short8 bF[4], aF[4];
#pragma unroll
    for (int n = 0; n < 4; ++n)
      bF[n] = *(const short8*)((const char*)&Bbuf[buf][(wn * 4 + n) * 512] + sb);
#pragma unroll
    for (int i = 0; i < 4; ++i)
      aF[i] = *(const short8*)((const char*)&Abuf[buf][(wm * 8 + i) * 512] + sb);
    if (st) stageA(t + 3);
    __builtin_amdgcn_s_barrier();
    asm volatile("s_waitcnt lgkmcnt(0)" ::: "memory");
    __builtin_amdgcn_sched_barrier(0);
    __builtin_amdgcn_s_setprio(1);
#pragma unroll
    for (int i = 0; i < 4; ++i)
#pragma unroll
      for (int n = 0; n < 4; ++n)
        acc[i][n] = __builtin_amdgcn_mfma_f32_16x16x32_bf16(aF[i], bF[n], acc[i][n], 0, 0, 0);
    __builtin_amdgcn_s_setprio(0);
    __builtin_amdgcn_s_barrier();

    // ---- phase 1: reads aF[4..7]; stage B(t+3); 16 MFMA; counted gate ------
    short8 aG[4];
#pragma unroll
    for (int i = 0; i < 4; ++i)
      aG[i] = *(const short8*)((const char*)&Abuf[buf][(wm * 8 + 4 + i) * 512] + sb);
    if (st) stageB(t + 3);
    __builtin_amdgcn_s_barrier();
    asm volatile("s_waitcnt lgkmcnt(0)" ::: "memory");
    __builtin_amdgcn_sched_barrier(0);
    __builtin_amdgcn_s_setprio(1);
#pragma unroll
    for (int i = 0; i < 4; ++i)
#pragma unroll
      for (int n = 0; n < 4; ++n)
        acc[4 + i][n] = __builtin_amdgcn_mfma_f32_16x16x32_bf16(aG[i], bF[n], acc[4 + i][n], 0, 0, 0);
    __builtin_amdgcn_s_setprio(0);
    if (st) { asm volatile("s_waitcnt vmcnt(4)" ::: "memory"); }
    else    { asm volatile("s_waitcnt vmcnt(0)" ::: "memory"); }
    __builtin_amdgcn_s_barrier();
  }

  // ---- epilogue: C/D layout col=lane&15, row=(lane>>4)*4+j ------------------
  const int ci = lane & 15;
  const int ri = g4 << 2;
  float bvv[4];
#pragma unroll
  for (int n = 0; n < 4; ++n) bvv[n] = bias[n0 + wn * 64 + n * 16 + ci];

  if (MODE == 2) {
#pragma unroll
    for (int n = 0; n < 4; ++n) {
      int col = n0 + wn * 64 + n * 16 + ci;
#pragma unroll
      for (int m = 0; m < 8; ++m) {
        int row0 = m0 + wm * 128 + m * 16 + ri;
        ushort4 pk;
        pk.x = f2b(acc[m][n][0] + bvv[n]);
        pk.y = f2b(acc[m][n][1] + bvv[n]);
        pk.z = f2b(acc[m][n][2] + bvv[n]);
        pk.w = f2b(acc[m][n][3] + bvv[n]);
        size_t addr = ((size_t)((row0 >> 10) * Hc + (col >> 7)) * 128 + (col & 127)) * 1024
                      + (row0 & 1023);
        *(ushort4*)(C + addr) = pk;
      }
    }
  } else {
#pragma unroll
    for (int m = 0; m < 8; ++m) {
      int row0 = m0 + wm * 128 + m * 16 + ri;
#pragma unroll
      for (int j = 0; j < 4; ++j) {
        u16* cp = C + (size_t)(row0 + j) * N + n0 + wn * 64 + ci;
#pragma unroll
        for (int n = 0; n < 4; ++n) {
          float v = acc[m][n][j] + bvv[n];
          if (MODE == 1) v = fmaxf(v, 0.f);
          cp[n * 16] = f2b(v);
        }
      }
    }
  }
}

// ---- MFMA flash attention --------------------------------------------------
// Block: 256 thr (4 waves). QBLK=128 (wave owns 32 q-rows), KVBLK=64.
__global__ __launch_bounds__(256, 2) void attn_mfma(
    const u16* __restrict__ qb,   // [B*S][D]
    const u16* __restrict__ kb,   // [B*S][D]
    const u16* __restrict__ vt,   // [B*H][128][1024]   (d, s)
    const u64* __restrict__ mb,   // [S][16] bitmask
    u16* __restrict__ ob)         // [B*S][D]
{
  __shared__ u16 Ks[64 * 128];    // 16 KB, byte ^= ((krow&7)<<4), row stride 256B
  __shared__ u16 Vts[128 * 64];   // 16 KB, byte ^= ((drow&7)<<4), row stride 128B
  __shared__ u16 Ps[4][32 * 64];  // 16 KB, per-wave P, row stride 128B

  const int bid = blockIdx.x;
  const int l   = (bid & 7) * 128 + (bid >> 3);   // XCD-chunked
  const int qt  = l & 7;
  const int bh  = l >> 3;
  const int h   = bh & (Hc - 1);
  const int b   = bh >> 4;
  const int q0  = qt * 128;

  const int tid  = threadIdx.x;
  const int lane = tid & 63;
  const int w    = tid >> 6;
  const int rowA = lane & 15;
  const int g4   = lane >> 4;
  const int kq16 = g4 << 3;
  const int ri   = g4 << 2;

  const size_t tokbase = (size_t)b * Sc * Dc + (size_t)h * Dhc;
  const size_t vtbase  = (size_t)bh * 128 * 1024;
  const int qwbase = q0 + w * 32;

  short8 qf[2][4];
#pragma unroll
  for (int m = 0; m < 2; ++m)
#pragma unroll
    for (int kk = 0; kk < 4; ++kk)
      qf[m][kk] = *reinterpret_cast<const short8*>(
          qb + tokbase + (size_t)(qwbase + m * 16 + rowA) * Dc + kk * 32 + kq16);

  f32x4 O[2][8];
#pragma unroll
  for (int m = 0; m < 2; ++m)
#pragma unroll
    for (int n = 0; n < 8; ++n) O[m][n] = (f32x4){0.f, 0.f, 0.f, 0.f};
  float mrow[2][4], lrow[2][4];
#pragma unroll
  for (int m = 0; m < 2; ++m)
#pragma unroll
    for (int j = 0; j < 4; ++j) { mrow[m][j] = -INFINITY; lrow[m][j] = 0.f; }

  const float scale = 0.08838834764831845f;   // 1/sqrt(128)

  for (int kt = 0; kt < Sc / 64; ++kt) {
    const int k0 = kt * 64;
    __syncthreads();
#pragma unroll
    for (int i = 0; i < 4; ++i) {
      int chunk = w * 4 + i;
      int gb = (chunk * 64 + lane) * 16;
      int L  = gb ^ (((gb >> 8) & 7) << 4);
      int row = L >> 8, ce = (L & 255) >> 1;
      GLOAD_LDS16(kb + tokbase + (size_t)(k0 + row) * Dc + ce, &Ks[chunk * 512]);
    }
#pragma unroll
    for (int i = 0; i < 4; ++i) {
      int chunk = w * 4 + i;
      int gb = (chunk * 64 + lane) * 16;
      int L  = gb ^ (((gb >> 7) & 7) << 4);
      int row = L >> 7, ce = (L & 127) >> 1;
      GLOAD_LDS16(vt + vtbase + (size_t)row * 1024 + k0 + ce, &Vts[chunk * 512]);
    }
    __syncthreads();

    f32x4 s[2][4];
#pragma unroll
    for (int m = 0; m < 2; ++m)
#pragma unroll
      for (int n = 0; n < 4; ++n) s[m][n] = (f32x4){0.f, 0.f, 0.f, 0.f};
#pragma unroll
    for (int kk = 0; kk < 4; ++kk) {
      short8 bfk[4];
#pragma unroll
      for (int n = 0; n < 4; ++n) {
        int krow = n * 16 + rowA;
        int by = (krow * 256 + kk * 64 + (g4 << 4)) ^ ((krow & 7) << 4);
        bfk[n] = *reinterpret_cast<const short8*>((const char*)Ks + by);
      }
#pragma unroll
      for (int m = 0; m < 2; ++m)
#pragma unroll
        for (int n = 0; n < 4; ++n)
          s[m][n] = __builtin_amdgcn_mfma_f32_16x16x32_bf16(qf[m][kk], bfk[n], s[m][n], 0, 0, 0);
    }

    float alpha[2][4];
#pragma unroll
    for (int m = 0; m < 2; ++m) {
      u64 wb_[4];
#pragma unroll
      for (int j = 0; j < 4; ++j)
        wb_[j] = mb[(size_t)(qwbase + m * 16 + ri + j) * 16 + kt];
#pragma unroll
      for (int j = 0; j < 4; ++j) {
        float pv[4];
        float mx = -3.0e38f;
#pragma unroll
        for (int n = 0; n < 4; ++n) {
          float x = s[m][n][j] * scale;
          if (!((wb_[j] >> (n * 16 + rowA)) & 1)) x = -1e9f;
          pv[n] = x;
          mx = fmaxf(mx, x);
        }
        mx = fmaxf(mx, __shfl_xor(mx, 1));
        mx = fmaxf(mx, __shfl_xor(mx, 2));
        mx = fmaxf(mx, __shfl_xor(mx, 4));
        mx = fmaxf(mx, __shfl_xor(mx, 8));
        float mnew = fmaxf(mrow[m][j], mx);
        float a = __expf(mrow[m][j] - mnew);
        mrow[m][j] = mnew;
        alpha[m][j] = a;
        float rs = 0.f;
#pragma unroll
        for (int n = 0; n < 4; ++n) {
          float p = __expf(pv[n] - mnew);
          pv[n] = p;
          rs += p;
        }
        rs += __shfl_xor(rs, 1);
        rs += __shfl_xor(rs, 2);
        rs += __shfl_xor(rs, 4);
        rs += __shfl_xor(rs, 8);
        lrow[m][j] = lrow[m][j] * a + rs;
        int prow = m * 16 + ri + j;
#pragma unroll
        for (int n = 0; n < 4; ++n) {
          int by = (prow * 128 + 2 * (n * 16 + rowA)) ^ ((prow & 7) << 4);
          *(u16*)((char*)Ps[w] + by) = f2b(pv[n]);
        }
      }
    }
    asm volatile("s_waitcnt lgkmcnt(0)" ::: "memory");

#pragma unroll
    for (int m = 0; m < 2; ++m)
#pragma unroll
      for (int n = 0; n < 8; ++n)
#pragma unroll
        for (int j = 0; j < 4; ++j) O[m][n][j] *= alpha[m][j];

    short8 pa[2][2];
#pragma unroll
    for (int m = 0; m < 2; ++m)
#pragma unroll
      for (int kk = 0; kk < 2; ++kk) {
        int prow = m * 16 + rowA;
        int by = (prow * 128 + kk * 64 + (g4 << 4)) ^ ((prow & 7) << 4);
        pa[m][kk] = *reinterpret_cast<const short8*>((const char*)Ps[w] + by);
      }
#pragma unroll
    for (int kk = 0; kk < 2; ++kk)
#pragma unroll
      for (int n = 0; n < 8; ++n) {
        int drow = n * 16 + rowA;
        int by = (drow * 128 + kk * 64 + (g4 << 4)) ^ ((drow & 7) << 4);
        short8 bfv = *reinterpret_cast<const short8*>((const char*)Vts + by);
#pragma unroll
        for (int m = 0; m < 2; ++m)
          O[m][n] = __builtin_amdgcn_mfma_f32_16x16x32_bf16(pa[m][kk], bfv, O[m][n], 0, 0, 0);
      }
  }

  float inv[2][4];
#pragma unroll
  for (int m = 0; m < 2; ++m)
#pragma unroll
    for (int j = 0; j < 4; ++j) inv[m][j] = 1.f / lrow[m][j];
#pragma unroll
  for (int m = 0; m < 2; ++m)
#pragma unroll
    for (int n = 0; n < 8; ++n) {
      int dcol = n * 16 + rowA;
#pragma unroll
      for (int j = 0; j < 4; ++j) {
        int qg = qwbase + m * 16 + ri + j;
        ob[tokbase + (size_t)qg * Dc + dcol] = f2b(O[m][n][j] * inv[m][j]);
      }
    }
}

// ---- fused residual + LayerNorm -------------------------------------------
template <int RES_BF16, int OUT_BF16>
__global__ __launch_bounds__(256) void ln_kernel(const u16* __restrict__ a,
                                                 const void* __restrict__ resid,
                                                 const float* __restrict__ g,
                                                 const float* __restrict__ be,
                                                 void* __restrict__ out) {
  int row = blockIdx.x;
  int tid = threadIdx.x;
  int c0  = tid << 3;

  float v[8], vr[8];
  uint4 ua = *(const uint4*)(a + (size_t)row * Dc + c0);
  unpack8(ua, v);
  if (RES_BF16) {
    uint4 ur = *(const uint4*)((const u16*)resid + (size_t)row * Dc + c0);
    unpack8(ur, vr);
  } else {
    const float* rp = (const float*)resid + (size_t)row * Dc + c0;
    float4 f0 = *(const float4*)rp;
    float4 f1 = *(const float4*)(rp + 4);
    vr[0] = f0.x; vr[1] = f0.y; vr[2] = f0.z; vr[3] = f0.w;
    vr[4] = f1.x; vr[5] = f1.y; vr[6] = f1.z; vr[7] = f1.w;
  }

  float s = 0.f, ss = 0.f;
#pragma unroll
  for (int j = 0; j < 8; ++j) {
    v[j] += vr[j];
    s += v[j];
    ss += v[j] * v[j];
  }
#pragma unroll
  for (int off = 32; off; off >>= 1) {
    s  += __shfl_down(s, off);
    ss += __shfl_down(ss, off);
  }
  __shared__ float rs[4], rss[4], stat[2];
  if ((tid & 63) == 0) { rs[tid >> 6] = s; rss[tid >> 6] = ss; }
  __syncthreads();
  if (tid == 0) {
    float t  = rs[0] + rs[1] + rs[2] + rs[3];
    float tt = rss[0] + rss[1] + rss[2] + rss[3];
    float mean = t * (1.f / Dc);
    float var  = tt * (1.f / Dc) - mean * mean;
    stat[0] = mean;
    stat[1] = rsqrtf(var + 1e-5f);
  }
  __syncthreads();
  float mean = stat[0], rstd = stat[1];

  float y[8];
#pragma unroll
  for (int j = 0; j < 8; ++j) y[j] = (v[j] - mean) * rstd * g[c0 + j] + be[c0 + j];

  if (OUT_BF16) {
    uint4 o;
    o.x = pack2(y[0], y[1]); o.y = pack2(y[2], y[3]);
    o.z = pack2(y[4], y[5]); o.w = pack2(y[6], y[7]);
    *(uint4*)((u16*)out + (size_t)row * Dc + c0) = o;
  } else {
    float* op = (float*)out + (size_t)row * Dc + c0;
    *(float4*)op       = (float4){y[0], y[1], y[2], y[3]};
    *(float4*)(op + 4) = (float4){y[4], y[5], y[6], y[7]};
  }
}

// ---------------------------------------------------------------------------
extern "C" void kernel_launch(void* const* d_in, const int* in_sizes, int n_in,
                              void* d_out, int out_size, void* d_ws, size_t ws_size,
                              hipStream_t stream) {
  (void)in_sizes; (void)n_in; (void)out_size; (void)ws_size;

  const float* x   = (const float*)d_in[0];
  const int*   mk  = (const int*)d_in[1];
  const float* Wq  = (const float*)d_in[2];
  const float* bq  = (const float*)d_in[3];
  const float* Wk  = (const float*)d_in[4];
  const float* bk  = (const float*)d_in[5];
  const float* Wv  = (const float*)d_in[6];
  const float* bv  = (const float*)d_in[7];
  const float* Wo  = (const float*)d_in[8];
  const float* bo  = (const float*)d_in[9];
  const float* W1  = (const float*)d_in[10];
  const float* b1  = (const float*)d_in[11];
  const float* W2  = (const float*)d_in[12];
  const float* b2  = (const float*)d_in[13];
  const float* g1  = (const float*)d_in[14];
  const float* be1 = (const float*)d_in[15];
  const float* g2  = (const float*)d_in[16];
  const float* be2 = (const float*)d_in[17];
  float* outp = (float*)d_out;

  // workspace arena: 8 regions x 32MB (bf16, 16777216 elems each). Peak 256MB.
  const size_t R = 16777216;
  u16* xb  = (u16*)d_ws;       // [0] x bf16 (dead after V gemm)
  u16* wb  = xb + R;           // [1] weight staging (reused per GEMM)
  u16* qb  = wb + R;           // [2] q
  u16* kb  = qb + R;           // [3] k
  u16* vt  = kb + R;           // [4] V transposed [B][H][128][1024]
  u16* ao  = vt + R;           // [5] attention out (pre-Wo)
  u64* mbt = (u64*)d_ws;       // [0] mask bitmask (after xb dead), 128 KB
  u16* ap  = qb;               // [2] attn projection (q dead)
  u16* x1  = kb;               // [3] post-LN1 (k dead)
  u16* hb  = vt;               // [4..7] FFN hidden 8192x8192 (vt, ao dead)
  u16* ffn = xb;               // [0] FFN out

  auto cvt = [&](const float* src, u16* dst, int n) {
    cvt_f32_bf16<<<dim3((n + 1023) / 1024), dim3(256), 0, stream>>>(src, dst, n);
  };

  cvt(x, xb, Mc * Dc);

  // QKV projections (V written directly in [b][h][d][s] transposed layout)
  cvt(Wq, wb, Dc * Dc);
  gemm256tb<0><<<dim3(32 * 8), dim3(512), 0, stream>>>(xb, wb, bq, qb, Mc, Dc, Dc);
  cvt(Wk, wb, Dc * Dc);
  gemm256tb<0><<<dim3(32 * 8), dim3(512), 0, stream>>>(xb, wb, bk, kb, Mc, Dc, Dc);
  cvt(Wv, wb, Dc * Dc);
  gemm256tb<2><<<dim3(32 * 8), dim3(512), 0, stream>>>(xb, wb, bv, vt, Mc, Dc, Dc);

  // mask bitmask (xb region is dead now)
  mask_bits<<<dim3(64), dim3(256), 0, stream>>>(mk, mbt);

  // attention
  attn_mfma<<<dim3(Bc * Hc * (Sc / 128)), dim3(256), 0, stream>>>(qb, kb, vt, mbt, ao);

  // output projection + LN1
  cvt(Wo, wb, Dc * Dc);
  gemm256tb<0><<<dim3(32 * 8), dim3(512), 0, stream>>>(ao, wb, bo, ap, Mc, Dc, Dc);
  ln_kernel<0, 1><<<dim3(Mc), dim3(256), 0, stream>>>(ap, x, g1, be1, x1);

  // FFN
  cvt(W1, wb, FFc * Dc);
  gemm256tb<1><<<dim3(32 * 32), dim3(512), 0, stream>>>(x1, wb, b1, hb, Mc, FFc, Dc);
  cvt(W2, wb, Dc * FFc);
  gemm256tb<0><<<dim3(32 * 8), dim3(512), 0, stream>>>(hb, wb, b2, ffn, Mc, Dc, FFc);
  ln_kernel<1, 0><<<dim3(Mc), dim3(256), 0, stream>>>(ffn, x1, g2, be2, outp);
}

// Round 9
// 1050.127 us; speedup vs baseline: 1.0887x; 1.0887x over previous
//
#include <hip/hip_runtime.h>
#include <cstdint>
#include <cstddef>

// ---------------------------------------------------------------------------
// EncoderLayer: B=8 S=1024 D=2048 H=16 Dh=128 FF=8192, fp32 in/out, bf16 compute
// ---------------------------------------------------------------------------

typedef unsigned short u16;
typedef unsigned int   u32;
typedef unsigned long long u64;
typedef __attribute__((ext_vector_type(8))) short short8;   // 8 x bf16 (4 VGPR)
typedef __attribute__((ext_vector_type(4))) float f32x4;

constexpr int Bc  = 8;
constexpr int Sc  = 1024;
constexpr int Dc  = 2048;
constexpr int Hc  = 16;
constexpr int Dhc = 128;
constexpr int FFc = 8192;
constexpr int Mc  = Bc * Sc;   // 8192 rows

// ---- bf16 helpers (manual, RNE) -------------------------------------------
__device__ __forceinline__ u16 f2b(float f) {
  u32 u = __builtin_bit_cast(u32, f);
  u += 0x7fffu + ((u >> 16) & 1u);
  return (u16)(u >> 16);
}
__device__ __forceinline__ u32 pack2(float a, float b) {
  return (u32)f2b(a) | ((u32)f2b(b) << 16);
}
__device__ __forceinline__ void unpack8(uint4 u, float* f) {
  u32 w[4] = {u.x, u.y, u.z, u.w};
#pragma unroll
  for (int i = 0; i < 4; ++i) {
    f[2 * i + 0] = __builtin_bit_cast(float, w[i] << 16);
    f[2 * i + 1] = __builtin_bit_cast(float, w[i] & 0xffff0000u);
  }
}

#define GLOAD_LDS16(gp, lp)                                                    \
  __builtin_amdgcn_global_load_lds(                                            \
      (const __attribute__((address_space(1))) void*)(gp),                     \
      (__attribute__((address_space(3))) void*)(lp), 16, 0, 0)

// ---- f32 -> bf16 conversion -----------------------------------------------
__global__ __launch_bounds__(256) void cvt_f32_bf16(const float* __restrict__ in,
                                                    u16* __restrict__ out, int n) {
  int i = (blockIdx.x * 256 + threadIdx.x) << 2;
  if (i >= n) return;
  float4 v = *(const float4*)(in + i);
  ushort4 o;
  o.x = f2b(v.x); o.y = f2b(v.y); o.z = f2b(v.z); o.w = f2b(v.w);
  *(ushort4*)(out + i) = o;
}

// ---- mask -> bitmask: mb[s][w] bit i = (mask[s][w*64+i] != 0) --------------
__global__ __launch_bounds__(256) void mask_bits(const int* __restrict__ mask,
                                                 u64* __restrict__ mb) {
  int t = blockIdx.x * 256 + threadIdx.x;   // 16384 = 1024 * 16
  int r = t >> 4, wd = t & 15;
  const int* p = mask + (size_t)r * Sc + wd * 64;
  u64 bits = 0;
#pragma unroll 16
  for (int i = 0; i < 64; i += 4) {
    int4 q = *(const int4*)(p + i);
    bits |= (u64)(q.x != 0) << (i + 0);
    bits |= (u64)(q.y != 0) << (i + 1);
    bits |= (u64)(q.z != 0) << (i + 2);
    bits |= (u64)(q.w != 0) << (i + 3);
  }
  mb[t] = bits;
}

// ---- 256x256 bf16 GEMM, register-prefetch pipeline (round-7 structure) -----
// 8 waves (2Mx4N), BK=32, 4 LDS tile buffers (128 KB), st_16x32 swizzle.
// Iteration t: ISSUE ds_reads of tile t+1's frags (no wait) + ISSUE staging of
// tile t+3 (carried pointers, no per-iter mults), then run 32 MFMA on tile t's
// frags already in registers (compiler emits counted lgkmcnt for the frag
// dependency -> next-tile LDS drain overlaps this tile's MFMA). ONE barrier
// per iteration. Gate vmcnt(4) steady / vmcnt(0) tail (round-5 race fix).
// No sched_barrier: MFMA doesn't depend on this iteration's issues, and
// order-pinning costs scheduler freedom (m141).
// MODE 0: bf16 out. MODE 1: ReLU + bf16 out.
// MODE 3: merged QKV epilogue — N=6144, seg = col>>11 selects {q, k, v^T}
//         output (v^T in [b][h][d][s] layout) and bias {b0,b1,b2}.
template <int MODE>
__global__ __launch_bounds__(512, 2) void gemm256tb(const u16* __restrict__ A,
                                                    const u16* __restrict__ Bt,
                                                    const float* __restrict__ bias,
                                                    const float* __restrict__ bias2,
                                                    const float* __restrict__ bias3,
                                                    u16* __restrict__ C,
                                                    int M, int N, int K) {
  __shared__ u16 Abuf[4][256 * 32];   // 64 KB
  __shared__ u16 Bbuf[4][256 * 32];   // 64 KB

  const int nbn = N >> 8;
  const int nwg = (M >> 8) * nbn;
  int bid = blockIdx.x;
  int sw = (bid & 7) * (nwg >> 3) + (bid >> 3);   // nwg multiple of 8 always
  const int m0 = (sw / nbn) << 8;
  const int n0 = (sw % nbn) << 8;

  const int tid  = threadIdx.x;
  const int lane = tid & 63;
  const int w    = tid >> 6;        // wave 0..7
  const int wm   = w >> 2;          // 0..1  (M half)
  const int wn   = w & 3;           // 0..3  (N quarter)

  const int rowA = lane & 15;
  const int g4   = lane >> 4;

  // Stage-source pre-swizzle (write side of st_16x32, inverse applied to the
  // per-lane global source so the LDS dest stays linear).
  const int p16  = lane << 4;
  const int wsw  = p16 ^ (((p16 >> 9) & 1) << 5);
  const int s_rr = wsw >> 6;            // row 0..15 within subtile
  const int s_cc = (wsw & 63) >> 1;     // col elem 0/8/16/24

  // ds_read swizzled byte offset within a 1024B subtile (read side)
  const int sb = (rowA * 64 + g4 * 16) ^ (((rowA >> 3) & 1) << 5);

  const int NT = K >> 5;   // K-tiles (64 or 256 here)

  // carried staging pointers (advance 32 elems per staged tile)
  const u16* aP = A  + (size_t)(m0 + w * 32 + s_rr) * K + s_cc;
  const u16* bP = Bt + (size_t)(n0 + w * 32 + s_rr) * K + s_cc;
  const size_t rstep = (size_t)16 * K;

  auto stage = [&](int tt, const u16* ap, const u16* bp) {
    int buf = tt & 3;
    GLOAD_LDS16(ap,         &Abuf[buf][(2 * w + 0) * 512]);
    GLOAD_LDS16(ap + rstep, &Abuf[buf][(2 * w + 1) * 512]);
    GLOAD_LDS16(bp,         &Bbuf[buf][(2 * w + 0) * 512]);
    GLOAD_LDS16(bp + rstep, &Bbuf[buf][(2 * w + 1) * 512]);
  };

  auto readF = [&](int tt, short8* aF, short8* bF) {
    int buf = tt & 3;
#pragma unroll
    for (int n = 0; n < 4; ++n)
      bF[n] = *(const short8*)((const char*)&Bbuf[buf][(wn * 4 + n) * 512] + sb);
#pragma unroll
    for (int i = 0; i < 8; ++i)
      aF[i] = *(const short8*)((const char*)&Abuf[buf][(wm * 8 + i) * 512] + sb);
  };

  f32x4 acc[8][4];
#pragma unroll
  for (int m = 0; m < 8; ++m)
#pragma unroll
    for (int n = 0; n < 4; ++n) acc[m][n] = (f32x4){0.f, 0.f, 0.f, 0.f};

  // Prologue: stage tiles 0,1,2 (12 gloads); vmcnt(4) -> tiles 0,1 landed.
  stage(0, aP, bP);
  stage(1, aP + 32, bP + 32);
  stage(2, aP + 64, bP + 64);
  aP += 96; bP += 96;
  asm volatile("s_waitcnt vmcnt(4)" ::: "memory");
  __builtin_amdgcn_s_barrier();

  short8 a0[8], b0[4], a1[8], b1[4];
  readF(0, a0, b0);

  auto body = [&](int t, short8* aC, short8* bC, short8* aN, short8* bN) {
    if (t + 1 < NT) readF(t + 1, aN, bN);     // issue next-tile frag reads
    if (t + 3 < NT) { stage(t + 3, aP, bP); aP += 32; bP += 32; }
    __builtin_amdgcn_s_setprio(1);
#pragma unroll
    for (int i = 0; i < 8; ++i)
#pragma unroll
      for (int n = 0; n < 4; ++n)
        acc[i][n] = __builtin_amdgcn_mfma_f32_16x16x32_bf16(aC[i], bC[n], acc[i][n], 0, 0, 0);
    __builtin_amdgcn_s_setprio(0);
    if (t + 3 < NT) { asm volatile("s_waitcnt vmcnt(4)" ::: "memory"); }
    else            { asm volatile("s_waitcnt vmcnt(0)" ::: "memory"); }
    __builtin_amdgcn_s_barrier();
  };

  for (int t = 0; t < NT; t += 2) {
    body(t,     a0, b0, a1, b1);
    body(t + 1, a1, b1, a0, b0);
  }

  // ---- epilogue: C/D layout col=lane&15, row=(lane>>4)*4+j ------------------
  const int ci = lane & 15;
  const int ri = g4 << 2;

  if (MODE == 3) {
    const int cb   = n0 + wn * 64;        // block-wave column base (0..6143)
    const int seg  = cb >> 11;            // 0=q, 1=k, 2=v^T
    const int cseg = cb & 2047;
    const float* bp_ = (seg == 0) ? bias : (seg == 1) ? bias2 : bias3;
    float bvv[4];
#pragma unroll
    for (int n = 0; n < 4; ++n) bvv[n] = bp_[cseg + n * 16 + ci];
    if (seg < 2) {
      u16* Cs = C + (size_t)seg * Mc * Dc;
#pragma unroll
      for (int m = 0; m < 8; ++m) {
        int row0 = m0 + wm * 128 + m * 16 + ri;
#pragma unroll
        for (int j = 0; j < 4; ++j) {
          u16* cp = Cs + (size_t)(row0 + j) * Dc + cseg + ci;
#pragma unroll
          for (int n = 0; n < 4; ++n)
            cp[n * 16] = f2b(acc[m][n][j] + bvv[n]);
        }
      }
    } else {
      u16* Cv = C + (size_t)2 * Mc * Dc;
#pragma unroll
      for (int n = 0; n < 4; ++n) {
        int col = cseg + n * 16 + ci;
#pragma unroll
        for (int m = 0; m < 8; ++m) {
          int row0 = m0 + wm * 128 + m * 16 + ri;
          ushort4 pk;
          pk.x = f2b(acc[m][n][0] + bvv[n]);
          pk.y = f2b(acc[m][n][1] + bvv[n]);
          pk.z = f2b(acc[m][n][2] + bvv[n]);
          pk.w = f2b(acc[m][n][3] + bvv[n]);
          size_t addr = ((size_t)((row0 >> 10) * Hc + (col >> 7)) * 128 + (col & 127)) * 1024
                        + (row0 & 1023);
          *(ushort4*)(Cv + addr) = pk;
        }
      }
    }
  } else {
    float bvv[4];
#pragma unroll
    for (int n = 0; n < 4; ++n) bvv[n] = bias[n0 + wn * 64 + n * 16 + ci];
#pragma unroll
    for (int m = 0; m < 8; ++m) {
      int row0 = m0 + wm * 128 + m * 16 + ri;
#pragma unroll
      for (int j = 0; j < 4; ++j) {
        u16* cp = C + (size_t)(row0 + j) * N + n0 + wn * 64 + ci;
#pragma unroll
        for (int n = 0; n < 4; ++n) {
          float v = acc[m][n][j] + bvv[n];
          if (MODE == 1) v = fmaxf(v, 0.f);
          cp[n * 16] = f2b(v);
        }
      }
    }
  }
}

// ---- MFMA flash attention --------------------------------------------------
// Block: 256 thr (4 waves). QBLK=128 (wave owns 32 q-rows), KVBLK=64.
__global__ __launch_bounds__(256, 2) void attn_mfma(
    const u16* __restrict__ qb,   // [B*S][D]
    const u16* __restrict__ kb,   // [B*S][D]
    const u16* __restrict__ vt,   // [B*H][128][1024]   (d, s)
    const u64* __restrict__ mb,   // [S][16] bitmask
    u16* __restrict__ ob)         // [B*S][D]
{
  __shared__ u16 Ks[64 * 128];    // 16 KB, byte ^= ((krow&7)<<4), row stride 256B
  __shared__ u16 Vts[128 * 64];   // 16 KB, byte ^= ((drow&7)<<4), row stride 128B
  __shared__ u16 Ps[4][32 * 64];  // 16 KB, per-wave P, row stride 128B

  const int bid = blockIdx.x;
  const int l   = (bid & 7) * 128 + (bid >> 3);   // XCD-chunked
  const int qt  = l & 7;
  const int bh  = l >> 3;
  const int h   = bh & (Hc - 1);
  const int b   = bh >> 4;
  const int q0  = qt * 128;

  const int tid  = threadIdx.x;
  const int lane = tid & 63;
  const int w    = tid >> 6;
  const int rowA = lane & 15;
  const int g4   = lane >> 4;
  const int kq16 = g4 << 3;
  const int ri   = g4 << 2;

  const size_t tokbase = (size_t)b * Sc * Dc + (size_t)h * Dhc;
  const size_t vtbase  = (size_t)bh * 128 * 1024;
  const int qwbase = q0 + w * 32;

  short8 qf[2][4];
#pragma unroll
  for (int m = 0; m < 2; ++m)
#pragma unroll
    for (int kk = 0; kk < 4; ++kk)
      qf[m][kk] = *reinterpret_cast<const short8*>(
          qb + tokbase + (size_t)(qwbase + m * 16 + rowA) * Dc + kk * 32 + kq16);

  f32x4 O[2][8];
#pragma unroll
  for (int m = 0; m < 2; ++m)
#pragma unroll
    for (int n = 0; n < 8; ++n) O[m][n] = (f32x4){0.f, 0.f, 0.f, 0.f};
  float mrow[2][4], lrow[2][4];
#pragma unroll
  for (int m = 0; m < 2; ++m)
#pragma unroll
    for (int j = 0; j < 4; ++j) { mrow[m][j] = -INFINITY; lrow[m][j] = 0.f; }

  const float scale = 0.08838834764831845f;   // 1/sqrt(128)

  for (int kt = 0; kt < Sc / 64; ++kt) {
    const int k0 = kt * 64;
    __syncthreads();
#pragma unroll
    for (int i = 0; i < 4; ++i) {
      int chunk = w * 4 + i;
      int gb = (chunk * 64 + lane) * 16;
      int L  = gb ^ (((gb >> 8) & 7) << 4);
      int row = L >> 8, ce = (L & 255) >> 1;
      GLOAD_LDS16(kb + tokbase + (size_t)(k0 + row) * Dc + ce, &Ks[chunk * 512]);
    }
#pragma unroll
    for (int i = 0; i < 4; ++i) {
      int chunk = w * 4 + i;
      int gb = (chunk * 64 + lane) * 16;
      int L  = gb ^ (((gb >> 7) & 7) << 4);
      int row = L >> 7, ce = (L & 127) >> 1;
      GLOAD_LDS16(vt + vtbase + (size_t)row * 1024 + k0 + ce, &Vts[chunk * 512]);
    }
    __syncthreads();

    f32x4 s[2][4];
#pragma unroll
    for (int m = 0; m < 2; ++m)
#pragma unroll
      for (int n = 0; n < 4; ++n) s[m][n] = (f32x4){0.f, 0.f, 0.f, 0.f};
#pragma unroll
    for (int kk = 0; kk < 4; ++kk) {
      short8 bfk[4];
#pragma unroll
      for (int n = 0; n < 4; ++n) {
        int krow = n * 16 + rowA;
        int by = (krow * 256 + kk * 64 + (g4 << 4)) ^ ((krow & 7) << 4);
        bfk[n] = *reinterpret_cast<const short8*>((const char*)Ks + by);
      }
#pragma unroll
      for (int m = 0; m < 2; ++m)
#pragma unroll
        for (int n = 0; n < 4; ++n)
          s[m][n] = __builtin_amdgcn_mfma_f32_16x16x32_bf16(qf[m][kk], bfk[n], s[m][n], 0, 0, 0);
    }

    float alpha[2][4];
#pragma unroll
    for (int m = 0; m < 2; ++m) {
      u64 wb_[4];
#pragma unroll
      for (int j = 0; j < 4; ++j)
        wb_[j] = mb[(size_t)(qwbase + m * 16 + ri + j) * 16 + kt];
#pragma unroll
      for (int j = 0; j < 4; ++j) {
        float pv[4];
        float mx = -3.0e38f;
#pragma unroll
        for (int n = 0; n < 4; ++n) {
          float x = s[m][n][j] * scale;
          if (!((wb_[j] >> (n * 16 + rowA)) & 1)) x = -1e9f;
          pv[n] = x;
          mx = fmaxf(mx, x);
        }
        mx = fmaxf(mx, __shfl_xor(mx, 1));
        mx = fmaxf(mx, __shfl_xor(mx, 2));
        mx = fmaxf(mx, __shfl_xor(mx, 4));
        mx = fmaxf(mx, __shfl_xor(mx, 8));
        float mnew = fmaxf(mrow[m][j], mx);
        float a = __expf(mrow[m][j] - mnew);
        mrow[m][j] = mnew;
        alpha[m][j] = a;
        float rs = 0.f;
#pragma unroll
        for (int n = 0; n < 4; ++n) {
          float p = __expf(pv[n] - mnew);
          pv[n] = p;
          rs += p;
        }
        rs += __shfl_xor(rs, 1);
        rs += __shfl_xor(rs, 2);
        rs += __shfl_xor(rs, 4);
        rs += __shfl_xor(rs, 8);
        lrow[m][j] = lrow[m][j] * a + rs;
        int prow = m * 16 + ri + j;
#pragma unroll
        for (int n = 0; n < 4; ++n) {
          int by = (prow * 128 + 2 * (n * 16 + rowA)) ^ ((prow & 7) << 4);
          *(u16*)((char*)Ps[w] + by) = f2b(pv[n]);
        }
      }
    }
    asm volatile("s_waitcnt lgkmcnt(0)" ::: "memory");

#pragma unroll
    for (int m = 0; m < 2; ++m)
#pragma unroll
      for (int n = 0; n < 8; ++n)
#pragma unroll
        for (int j = 0; j < 4; ++j) O[m][n][j] *= alpha[m][j];

    short8 pa[2][2];
#pragma unroll
    for (int m = 0; m < 2; ++m)
#pragma unroll
      for (int kk = 0; kk < 2; ++kk) {
        int prow = m * 16 + rowA;
        int by = (prow * 128 + kk * 64 + (g4 << 4)) ^ ((prow & 7) << 4);
        pa[m][kk] = *reinterpret_cast<const short8*>((const char*)Ps[w] + by);
      }
#pragma unroll
    for (int kk = 0; kk < 2; ++kk)
#pragma unroll
      for (int n = 0; n < 8; ++n) {
        int drow = n * 16 + rowA;
        int by = (drow * 128 + kk * 64 + (g4 << 4)) ^ ((drow & 7) << 4);
        short8 bfv = *reinterpret_cast<const short8*>((const char*)Vts + by);
#pragma unroll
        for (int m = 0; m < 2; ++m)
          O[m][n] = __builtin_amdgcn_mfma_f32_16x16x32_bf16(pa[m][kk], bfv, O[m][n], 0, 0, 0);
      }
  }

  float inv[2][4];
#pragma unroll
  for (int m = 0; m < 2; ++m)
#pragma unroll
    for (int j = 0; j < 4; ++j) inv[m][j] = 1.f / lrow[m][j];
#pragma unroll
  for (int m = 0; m < 2; ++m)
#pragma unroll
    for (int n = 0; n < 8; ++n) {
      int dcol = n * 16 + rowA;
#pragma unroll
      for (int j = 0; j < 4; ++j) {
        int qg = qwbase + m * 16 + ri + j;
        ob[tokbase + (size_t)qg * Dc + dcol] = f2b(O[m][n][j] * inv[m][j]);
      }
    }
}

// ---- fused residual + LayerNorm -------------------------------------------
template <int RES_BF16, int OUT_BF16>
__global__ __launch_bounds__(256) void ln_kernel(const u16* __restrict__ a,
                                                 const void* __restrict__ resid,
                                                 const float* __restrict__ g,
                                                 const float* __restrict__ be,
                                                 void* __restrict__ out) {
  int row = blockIdx.x;
  int tid = threadIdx.x;
  int c0  = tid << 3;

  float v[8], vr[8];
  uint4 ua = *(const uint4*)(a + (size_t)row * Dc + c0);
  unpack8(ua, v);
  if (RES_BF16) {
    uint4 ur = *(const uint4*)((const u16*)resid + (size_t)row * Dc + c0);
    unpack8(ur, vr);
  } else {
    const float* rp = (const float*)resid + (size_t)row * Dc + c0;
    float4 f0 = *(const float4*)rp;
    float4 f1 = *(const float4*)(rp + 4);
    vr[0] = f0.x; vr[1] = f0.y; vr[2] = f0.z; vr[3] = f0.w;
    vr[4] = f1.x; vr[5] = f1.y; vr[6] = f1.z; vr[7] = f1.w;
  }

  float s = 0.f, ss = 0.f;
#pragma unroll
  for (int j = 0; j < 8; ++j) {
    v[j] += vr[j];
    s += v[j];
    ss += v[j] * v[j];
  }
#pragma unroll
  for (int off = 32; off; off >>= 1) {
    s  += __shfl_down(s, off);
    ss += __shfl_down(ss, off);
  }
  __shared__ float rs[4], rss[4], stat[2];
  if ((tid & 63) == 0) { rs[tid >> 6] = s; rss[tid >> 6] = ss; }
  __syncthreads();
  if (tid == 0) {
    float t  = rs[0] + rs[1] + rs[2] + rs[3];
    float tt = rss[0] + rss[1] + rss[2] + rss[3];
    float mean = t * (1.f / Dc);
    float var  = tt * (1.f / Dc) - mean * mean;
    stat[0] = mean;
    stat[1] = rsqrtf(var + 1e-5f);
  }
  __syncthreads();
  float mean = stat[0], rstd = stat[1];

  float y[8];
#pragma unroll
  for (int j = 0; j < 8; ++j) y[j] = (v[j] - mean) * rstd * g[c0 + j] + be[c0 + j];

  if (OUT_BF16) {
    uint4 o;
    o.x = pack2(y[0], y[1]); o.y = pack2(y[2], y[3]);
    o.z = pack2(y[4], y[5]); o.w = pack2(y[6], y[7]);
    *(uint4*)((u16*)out + (size_t)row * Dc + c0) = o;
  } else {
    float* op = (float*)out + (size_t)row * Dc + c0;
    *(float4*)op       = (float4){y[0], y[1], y[2], y[3]};
    *(float4*)(op + 4) = (float4){y[4], y[5], y[6], y[7]};
  }
}

// ---------------------------------------------------------------------------
extern "C" void kernel_launch(void* const* d_in, const int* in_sizes, int n_in,
                              void* d_out, int out_size, void* d_ws, size_t ws_size,
                              hipStream_t stream) {
  (void)in_sizes; (void)n_in; (void)out_size; (void)ws_size;

  const float* x   = (const float*)d_in[0];
  const int*   mk  = (const int*)d_in[1];
  const float* Wq  = (const float*)d_in[2];
  const float* bq  = (const float*)d_in[3];
  const float* Wk  = (const float*)d_in[4];
  const float* bk  = (const float*)d_in[5];
  const float* Wv  = (const float*)d_in[6];
  const float* bv  = (const float*)d_in[7];
  const float* Wo  = (const float*)d_in[8];
  const float* bo  = (const float*)d_in[9];
  const float* W1  = (const float*)d_in[10];
  const float* b1  = (const float*)d_in[11];
  const float* W2  = (const float*)d_in[12];
  const float* b2  = (const float*)d_in[13];
  const float* g1  = (const float*)d_in[14];
  const float* be1 = (const float*)d_in[15];
  const float* g2  = (const float*)d_in[16];
  const float* be2 = (const float*)d_in[17];
  float* outp = (float*)d_out;

  // workspace arena: 8 regions x 32MB (R = 16777216 bf16 elems each).
  // live-range ledger:
  // [0] xb (QKV-A) -> W1 staging (xb dead after QKV gemm)
  // [1] wqkv (24MB, [Wq|Wk|Wv]) + mbt @ +13M elems -> ffn out (FFN2; both dead)
  // [2] qb   -> hb[0]   (q dead after attn)
  // [3] kb   -> hb[1]
  // [4] vt   -> hb[2]
  // [5] ao   -> hb[3]   (ao dead after Wo gemm; hb written at FFN1)
  // [6] Wo staging (8MB) -> x1 (Wo-staging dead after Wo gemm; x1 lives to LN2)
  // [7] ap (Wo out) -> W2 staging (ap dead after LN1)
  const size_t R = 16777216;
  u16* xb   = (u16*)d_ws;
  u16* wqkv = xb + R;            // [1]: 3 x 2048x2048 bf16 = 12.58M elems
  u64* mbt  = (u64*)(wqkv + 13 * 1024 * 1024);   // [1]+26MB, 128 KB
  u16* qb   = xb + 2 * R;        // [2] (kb = qb+Mc*Dc, vt = qb+2*Mc*Dc)
  u16* ao   = xb + 5 * R;        // [5]
  u16* wst6 = xb + 6 * R;        // [6] Wo staging
  u16* x1   = xb + 6 * R;        // [6] after Wo gemm
  u16* ap   = xb + 7 * R;        // [7]
  u16* w1s  = xb;                // [0] W1 staging (xb dead)
  u16* hb   = xb + 2 * R;        // [2..5] FFN hidden 8192x8192
  u16* w2s  = xb + 7 * R;        // [7] W2 staging (ap dead)
  u16* ffn  = wqkv;              // [1] FFN2 out (wqkv+mbt dead)

  const size_t MD = (size_t)Mc * Dc;

  auto cvt = [&](const float* src, u16* dst, int n) {
    cvt_f32_bf16<<<dim3((n + 1023) / 1024), dim3(256), 0, stream>>>(src, dst, n);
  };

  cvt(x, xb, Mc * Dc);
  cvt(Wq, wqkv,               Dc * Dc);
  cvt(Wk, wqkv + Dc * Dc,     Dc * Dc);
  cvt(Wv, wqkv + 2 * Dc * Dc, Dc * Dc);

  // merged QKV projection: C segments {q, k, v^T} at qb, qb+MD, qb+2MD
  gemm256tb<3><<<dim3(32 * 24), dim3(512), 0, stream>>>(xb, wqkv, bq, bk, bv,
                                                        qb, Mc, 3 * Dc, Dc);

  mask_bits<<<dim3(64), dim3(256), 0, stream>>>(mk, mbt);

  // attention
  attn_mfma<<<dim3(Bc * Hc * (Sc / 128)), dim3(256), 0, stream>>>(
      qb, qb + MD, qb + 2 * MD, mbt, ao);

  // output projection + LN1
  cvt(Wo, wst6, Dc * Dc);
  gemm256tb<0><<<dim3(32 * 8), dim3(512), 0, stream>>>(ao, wst6, bo, bo, bo,
                                                       ap, Mc, Dc, Dc);
  ln_kernel<0, 1><<<dim3(Mc), dim3(256), 0, stream>>>(ap, x, g1, be1, x1);

  // FFN
  cvt(W1, w1s, FFc * Dc);
  gemm256tb<1><<<dim3(32 * 32), dim3(512), 0, stream>>>(x1, w1s, b1, b1, b1,
                                                        hb, Mc, FFc, Dc);
  cvt(W2, w2s, Dc * FFc);
  gemm256tb<0><<<dim3(32 * 8), dim3(512), 0, stream>>>(hb, w2s, b2, b2, b2,
                                                       ffn, Mc, Dc, FFc);
  ln_kernel<1, 0><<<dim3(Mc), dim3(256), 0, stream>>>(ffn, x1, g2, be2, outp);
}